// Round 11
// baseline (161.985 us; speedup 1.0000x reference)
//
#include <hip/hip_runtime.h>

// HausdorffDTLoss: exact separable EDT (fg & bg) per image, then
// mean((pred-target)^2 * (pred_dt^2 + target_dt^2)).
// Envelope identity: g[i] = min_j f[j]+(i-j)^2 = i^2 + min_j (h[j]-2ij),
// h[j]=f[j]+j^2. All intermediates are integers, |val| < 2^17 -> u16 storage,
// fp32 math exact (R1-R18: absmax 0.0).
// R12 windowing: scan only |i-j| <= W, W = ceil(sqrt(max f over outputs)) --
// exact for any input (j=i in-window; outside candidates >= f(i) >= g(i)).
//
// R20. R19 FAILED correctness (absmax 4959): grid-barrier fusion assumed
// 1024 co-resident blocks, but 512thr = 8 waves -> 4 blocks/CU would be 100%
// occupancy; measured ~50% = ~2 blocks/CU -> not co-resident -> spin timeout
// -> stale ws. The occupancy query (cap<4) was RIGHT; fusion is abandoned.
// Revert to the proven 2-dispatch path (R18 fallback, 149.5us) and recover
// the round with a safe cut: MERGE zy's polarities. The bg site mask is the
// complement of the fg mask, so one block stages the slab ONCE, ballots once,
// then runs z-EDT+envelope for pol0 (masks ~bm) and pol1 (masks bm)
// sequentially, reusing hz with 2 extra barriers. zy HBM reads halve
// (33.6 -> 16.8MB); one stage+ballot pass per slab removed; 512 blocks.
// xloss body byte-identical to R18 (proven 46us).

constexpr int BIGI = 49153;      // 3*128^2+1, matches reference BIG exactly
constexpr int NVOX = 4194304;    // voxels per tensor (2 samples x 128^3)
constexpr int STZ  = 129;        // zy dword row stride: 129%32=1 -> 2-way max (free)
constexpr int STX  = 65;         // xloss dword row stride: 65%32=1 -> same property
constexpr int LDSW = 512 + 65 * STZ;   // bm(256 u64 = 512 w) + hz(65*129 w) = 35.6KB

// Windowed pair-packed lower-envelope into acc[16] at outputs i0..i0+15.
// p = column c of a [65*stride] u32 LDS array of packed u16 h-values
// (row 64 = slack for the 1-ahead prefetch). R14 proven form.
__device__ __forceinline__ void envelope_win(const unsigned int* __restrict__ p,
                                             const int stride, const float i0f,
                                             const int qlo, const int qhi,
                                             float acc[16]) {
    unsigned int vc = p[qlo * stride];
    float jm2 = -4.0f * (float)qlo;            // -2*(2q)
    for (int q = qlo; q <= qhi; ++q) {
        unsigned int vn = p[(q + 1) * stride]; // 1-pair prefetch (slack row)
        float h0 = (float)(vc & 0xffffu);      // j = 2q
        float h1 = (float)(vc >> 16);          // j = 2q+1
        float jb = jm2 - 2.0f;
        float c0 = fmaf(jm2, i0f, h0);         // candidate at i = i0
        float c1 = fmaf(jb,  i0f, h1);
#pragma unroll
        for (int k = 0; k < 16; ++k) {
            acc[k] = fminf(acc[k], fminf(c0, c1));
            c0 += jm2; c1 += jb;               // exact: integers < 2^17
        }
        jm2 -= 4.0f;
        vc = vn;
    }
}

// Wave-uniform window W from the wave's 16 output rows' f-values (pair-packed
// layout; f = h - i^2), wave-maxed. Guarantees W*W >= fmax.
__device__ __forceinline__ int window_of(const unsigned int* __restrict__ p,
                                         const int stride, const int i0) {
    int fmx = 0;
#pragma unroll
    for (int m = 0; m < 8; ++m) {
        unsigned int v = p[((i0 >> 1) + m) * stride];
        int y0 = i0 + 2 * m, y1 = y0 + 1;
        int f0 = (int)(v & 0xffffu) - y0 * y0;
        int f1 = (int)(v >> 16) - y1 * y1;
        fmx = max(fmx, max(f0, f1));
    }
#pragma unroll
    for (int off = 32; off; off >>= 1) fmx = max(fmx, __shfl_xor(fmx, off));
    int W = (int)sqrtf((float)fmx);            // fmx <= 49153, exact in fp32
    W += (W * W < fmx);
    W += (W * W < fmx);                        // guarantees W*W >= fmx
    return W;
}

// Dual-polarity zy: binarize + bitmask z-EDT + windowed y-envelope for one
// (b,x) slab of one image, BOTH polarities sequentially (bg mask = ~fg mask).
// 512 thr, 35.6KB LDS. Grid 512 = (img, b*x). Stores g + x^2 (u16).
__global__ __launch_bounds__(512) void zy_kernel(const float* __restrict__ pred,
                                                 const float* __restrict__ tgt,
                                                 unsigned short* __restrict__ ws,
                                                 float* __restrict__ out) {
    __shared__ __align__(16) unsigned int lds[LDSW];
    unsigned long long* bm = (unsigned long long*)lds;   // 256 u64 fg site masks
    unsigned int* hz = lds + 512;                        // 65*STZ packed pairs
    const int t   = blockIdx.x;                    // 0..511
    const int img = t & 1;
    const int s   = t >> 1;                        // 0..255: b(2) x x(128)
    const int b   = s >> 7;
    const int x   = s & 127;
    const int sb  = (b * 128 + x) * 16384;         // + y*128 + z
    const int tid = threadIdx.x;
    const float* im = img ? tgt : pred;
    if (t == 0 && tid == 0) out[0] = 0.0f;         // done before xloss dispatch

    // ---- stage ONCE: batch 32 slab loads (two-phase, proven R14/R17) ----
    float vreg[32];
#pragma unroll
    for (int k = 0; k < 32; ++k) vreg[k] = im[sb + tid + k * 512];

    // ---- ballots ONCE: fg site bitmasks (bg masks = complement) ----
#pragma unroll
    for (int k = 0; k < 32; ++k) {
        bool fg = vreg[k] > 0.5f;
        unsigned long long bal = __ballot(fg);
        if ((tid & 63) == 0) bm[(tid + k * 512) >> 6] = bal; // uniform per wave
    }
    __syncthreads();

    unsigned short* hu = (unsigned short*)hz;
    const int z = tid & 127;                       // fixed per thread, uniform/wave
    const int c = tid & 127;
    const int xsq = x * x;

    // ---- both polarities sequentially, reusing bm (read-only) and hz ----
#pragma clang loop unroll(disable)
    for (int pol = 0; pol < 2; ++pol) {            // 0: fg EDT (sites=~fg), 1: bg
        // parallel z-EDT: per-voxel nearest-site distance from the masks
#pragma unroll
        for (int k = 0; k < 32; ++k) {
            int y = (tid >> 7) + k * 4;
            unsigned long long b0 = bm[2 * y], b1 = bm[2 * y + 1];
            unsigned long long m0 = pol ? b0 : ~b0;  // block-uniform select
            unsigned long long m1 = pol ? b1 : ~b1;
            int d;
            if (z < 64) {
                unsigned long long lm = m0 << (63 - z);
                unsigned long long rm = m0 >> z;
                int dfwd = lm ? __builtin_clzll(lm) : 999;
                int db0  = rm ? __builtin_ctzll(rm) : 999;
                int db1  = (m1 ? __builtin_ctzll(m1) : 999) + (64 - z);
                d = min(dfwd, min(db0, db1));
            } else {
                int zz = z - 64;
                unsigned long long lm = m1 << (63 - zz);
                unsigned long long rm = m1 >> zz;
                int df1 = lm ? __builtin_clzll(lm) : 999;
                int df0 = (m0 ? __builtin_clzll(m0) : 999) + zz + 1;
                int dbw = rm ? __builtin_ctzll(rm) : 999;
                d = min(min(df1, df0), dbw);
            }
            int f = (d <= 127) ? d * d : BIGI;     // empty line -> BIG (exact)
            hu[((y >> 1) * STZ) * 2 + (y & 1) + 2 * z] = (unsigned short)(f + y * y);
        }
        __syncthreads();

        // y-envelope: c = z column, 4 groups x 2 rounds; store g + x^2 (u16)
        unsigned short* outv = ws + (size_t)(img * 2 + pol) * NVOX + sb;
#pragma clang loop unroll(disable)
        for (int r = 0; r < 2; ++r) {              // one acc[16] live at a time
            const int i0 = (tid >> 7) * 16 + r * 64;   // wave-uniform (tid>>7)
            const float i0f = (float)i0;
            const int W = window_of(hz + c, STZ, i0);
            const int qlo = __builtin_amdgcn_readfirstlane(max(0, (i0 - W) >> 1));
            const int qhi = __builtin_amdgcn_readfirstlane(min(63, (i0 + 15 + W) >> 1));
            float acc[16];
#pragma unroll
            for (int k = 0; k < 16; ++k) acc[k] = 3.0e38f;
            envelope_win(hz + c, STZ, i0f, qlo, qhi, acc);
#pragma unroll
            for (int k = 0; k < 16; ++k) {         // g + x^2 <= 65282: u16
                float iif = i0f + (float)k;
                outv[(i0 + k) * 128 + c] =
                    (unsigned short)((unsigned int)fmaf(iif, iif, acc[k]) + xsq);
            }
        }
        if (pol == 0) __syncthreads();             // hz reused by pol1 z-EDT
    }
}

// Fused dual-polarity x-envelope + loss partial (R18 proven body).
// 64-col tiles, 512 thr, 33.6KB LDS. Grid 1024 = (img, b, 256 tiles).
__global__ __launch_bounds__(512) void xloss_kernel(const float* __restrict__ pred,
                                                    const float* __restrict__ tgt,
                                                    const unsigned short* __restrict__ ws,
                                                    float* __restrict__ out) {
    __shared__ __align__(16) unsigned int hx[129 * STX];   // 128 rows + 1 slack
    __shared__ float red[8];
    const int t    = blockIdx.x;
    const int img  = t & 1;                    // adjacent blocks share pred/tgt
    const int b    = (t >> 1) & 1;
    const int q0   = (t >> 2) * 64;            // (y,z) tile base, 0..16320
    const int base = b * 2097152 + q0;         // + x*16384 + c
    const int tid  = threadIdx.x;
    const int c    = tid & 63;
    const int i0   = (tid >> 6) * 16;          // wave-uniform (64 lanes = 64 cols)
    const float i0f = (float)i0;
    const unsigned short* A16 = ws + (size_t)(img * 2) * NVOX;
    const unsigned int* A32 = (const unsigned int*)(A16 + base);       // base even
    const unsigned int* B32 = (const unsigned int*)(A16 + NVOX + base);

    // hoisted scattered pred/tgt loads: latency hides under the scan
    float dv[16];
#pragma unroll
    for (int k = 0; k < 16; ++k) {
        int v = base + (i0 + k) * 16384 + c;   // 256B contiguous per wave
        dv[k] = pred[v] - tgt[v];
    }

    // stage BOTH volumes, u32 in AND out: word[j][c] = hA | hB<<16
#pragma unroll
    for (int k = 0; k < 8; ++k) {
        int l = tid + k * 512;                 // 0..4095
        int j = l >> 5, cp = l & 31;           // row j, u32 col-pair (c=2cp,2cp+1)
        unsigned int va = A32[j * 8192 + cp];
        unsigned int vb = B32[j * 8192 + cp];
        int w0 = j * STX + 2 * cp;
        hx[w0]     = (va & 0xffffu) | (vb << 16);          // col 2cp
        hx[w0 + 1] = (va >> 16)    | (vb & 0xffff0000u);   // col 2cp+1
    }
    __syncthreads();

    // window over both polarities + no-fg guard from fmxB
    const unsigned int* p = hx + c;
    int fmxA = 0, fmxB = 0;
#pragma unroll
    for (int m = 0; m < 16; ++m) {
        int j = i0 + m;
        unsigned int w = p[j * STX];
        fmxA = max(fmxA, (int)(w & 0xffffu) - j * j);  // f = h - j^2 >= 0
        fmxB = max(fmxB, (int)(w >> 16) - j * j);
    }
    int fmx = max(fmxA, fmxB);
#pragma unroll
    for (int off = 32; off; off >>= 1) {
        fmx  = max(fmx,  __shfl_xor(fmx,  off));
        fmxB = max(fmxB, __shfl_xor(fmxB, off));
    }
    int W = (int)sqrtf((float)fmx);
    W += (W * W < fmx);
    W += (W * W < fmx);                        // W*W >= fmx
    const int jlo = __builtin_amdgcn_readfirstlane(max(0, i0 - W));
    const int jhi = __builtin_amdgcn_readfirstlane(min(127, i0 + 15 + W));
    // bg-EDT f == BIGI uniformly iff sample has no fg (else <= 48387 < BIGI)
    const bool nofg = (fmxB >= BIGI);

    // fused scan: accA (pol0) + accB (pol1) in one pass, 1-ahead
    float accA[16], accB[16];
#pragma unroll
    for (int k = 0; k < 16; ++k) { accA[k] = 3.0e38f; accB[k] = 3.0e38f; }
    unsigned int vc = p[jlo * STX];
    float jm = -2.0f * (float)jlo;
    for (int j = jlo; j <= jhi; ++j) {
        unsigned int vn = p[(j + 1) * STX];    // row 128 slack exists
        float hA = (float)(vc & 0xffffu);
        float hB = (float)(vc >> 16);
        float cA = fmaf(jm, i0f, hA);          // candidate at i = i0
        float cB = fmaf(jm, i0f, hB);
#pragma unroll
        for (int k = 0; k < 16; ++k) {
            accA[k] = fminf(accA[k], cA);
            accB[k] = fminf(accB[k], cB);
            cA += jm; cB += jm;                // exact: integers < 2^17
        }
        jm -= 2.0f;
        vc = vn;
    }

    // loss partial: (p-t)^2 * (sqrt(gA)+sqrt(gB))^2 * guard
    // (sqrt-then-square kept: reference computes (sqrt g)**2, bit-compat)
    float s = 0.0f;
#pragma unroll
    for (int k = 0; k < 16; ++k) {
        float iif = i0f + (float)k;
        float gA = fmaf(iif, iif, accA[k]);
        float gB = fmaf(iif, iif, accB[k]);
        float d = dv[k];
        float fld = sqrtf(gA) + sqrtf(gB);
        s += d * d * fld * fld;
    }
    if (nofg) s = 0.0f;
#pragma unroll
    for (int off = 32; off > 0; off >>= 1) s += __shfl_down(s, off);
    if ((tid & 63) == 0) red[tid >> 6] = s;
    __syncthreads();
    if (tid == 0) {
        float tot = 0.0f;
#pragma unroll
        for (int w = 0; w < 8; ++w) tot += red[w];
        atomicAdd(out, tot * (1.0f / 4194304.0f));
    }
}

extern "C" void kernel_launch(void* const* d_in, const int* in_sizes, int n_in,
                              void* d_out, int out_size, void* d_ws, size_t ws_size,
                              hipStream_t stream) {
    const float* pred = (const float*)d_in[0];
    const float* tgt  = (const float*)d_in[1];
    float* out = (float*)d_out;
    unsigned short* ws16 = (unsigned short*)d_ws;      // 4 u16 volumes = 33.6 MB

    zy_kernel<<<dim3(512), 512, 0, stream>>>(pred, tgt, ws16, out);
    xloss_kernel<<<dim3(1024), 512, 0, stream>>>(pred, tgt, ws16, out);
}

// Round 12
// 159.552 us; speedup vs baseline: 1.0152x; 1.0152x over previous
//
#include <hip/hip_runtime.h>

// HausdorffDTLoss: exact separable EDT (fg & bg) per image, then
// mean((pred-target)^2 * (pred_dt^2 + target_dt^2)).
// Envelope identity: g[i] = min_j f[j]+(i-j)^2 = i^2 + min_j (h[j]-2ij),
// h[j]=f[j]+j^2. All intermediates are integers, |val| < 2^17 -> u16 storage,
// fp32 math exact (R1-R20: absmax 0.0).
// R12 windowing: scan only |i-j| <= W, W = ceil(sqrt(max f over outputs)) --
// exact for any input (j=i in-window; outside candidates >= f(i) >= g(i)).
//
// R21. R20's polarity merge halved zy FETCH (32.9->16.5MB, predicted) but
// REGRESSED time (46->57-61us): 512 blocks x 8 waves = 16 waves/CU (19%
// occupancy) -- parallelism was halved with merge. Fix the packaging, keep
// the merge: 1024-THREAD blocks. 512 blocks x 16 waves -> 2 blocks/CU
// (thread-capped) = 32 waves/CU = 100% occupancy, 2x R18's in-flight waves.
// Stage 16 loads/thread, 16 ballots, z-EDT 16 rows/thread, y-envelope in ONE
// round (8 wave-groups x 16 rows; i0=(tid>>7)*16 wave-uniform) -> one acc[16]
// live, VGPR ~50 (vs R20's 76). Per-CU work = R18 minus duplicated stage.
// xloss byte-identical (proven 46us).

constexpr int BIGI = 49153;      // 3*128^2+1, matches reference BIG exactly
constexpr int NVOX = 4194304;    // voxels per tensor (2 samples x 128^3)
constexpr int STZ  = 129;        // zy dword row stride: 129%32=1 -> 2-way max (free)
constexpr int STX  = 65;         // xloss dword row stride: 65%32=1 -> same property
constexpr int LDSW = 512 + 65 * STZ;   // bm(256 u64 = 512 w) + hz(65*129 w) = 35.6KB

// Windowed pair-packed lower-envelope into acc[16] at outputs i0..i0+15.
// p = column c of a [65*stride] u32 LDS array of packed u16 h-values
// (row 64 = slack for the 1-ahead prefetch). R14 proven form.
__device__ __forceinline__ void envelope_win(const unsigned int* __restrict__ p,
                                             const int stride, const float i0f,
                                             const int qlo, const int qhi,
                                             float acc[16]) {
    unsigned int vc = p[qlo * stride];
    float jm2 = -4.0f * (float)qlo;            // -2*(2q)
    for (int q = qlo; q <= qhi; ++q) {
        unsigned int vn = p[(q + 1) * stride]; // 1-pair prefetch (slack row)
        float h0 = (float)(vc & 0xffffu);      // j = 2q
        float h1 = (float)(vc >> 16);          // j = 2q+1
        float jb = jm2 - 2.0f;
        float c0 = fmaf(jm2, i0f, h0);         // candidate at i = i0
        float c1 = fmaf(jb,  i0f, h1);
#pragma unroll
        for (int k = 0; k < 16; ++k) {
            acc[k] = fminf(acc[k], fminf(c0, c1));
            c0 += jm2; c1 += jb;               // exact: integers < 2^17
        }
        jm2 -= 4.0f;
        vc = vn;
    }
}

// Wave-uniform window W from the wave's 16 output rows' f-values (pair-packed
// layout; f = h - i^2), wave-maxed. Guarantees W*W >= fmax.
__device__ __forceinline__ int window_of(const unsigned int* __restrict__ p,
                                         const int stride, const int i0) {
    int fmx = 0;
#pragma unroll
    for (int m = 0; m < 8; ++m) {
        unsigned int v = p[((i0 >> 1) + m) * stride];
        int y0 = i0 + 2 * m, y1 = y0 + 1;
        int f0 = (int)(v & 0xffffu) - y0 * y0;
        int f1 = (int)(v >> 16) - y1 * y1;
        fmx = max(fmx, max(f0, f1));
    }
#pragma unroll
    for (int off = 32; off; off >>= 1) fmx = max(fmx, __shfl_xor(fmx, off));
    int W = (int)sqrtf((float)fmx);            // fmx <= 49153, exact in fp32
    W += (W * W < fmx);
    W += (W * W < fmx);                        // guarantees W*W >= fmx
    return W;
}

// Dual-polarity zy, 1024 threads: binarize + bitmask z-EDT + y-envelope for
// one (b,x) slab of one image, BOTH polarities (bg mask = ~fg mask).
// 512 blocks x 16 waves = 2 blocks/CU = 100% occupancy. 35.6KB LDS.
__global__ __launch_bounds__(1024) void zy_kernel(const float* __restrict__ pred,
                                                  const float* __restrict__ tgt,
                                                  unsigned short* __restrict__ ws,
                                                  float* __restrict__ out) {
    __shared__ __align__(16) unsigned int lds[LDSW];
    unsigned long long* bm = (unsigned long long*)lds;   // 256 u64 fg site masks
    unsigned int* hz = lds + 512;                        // 65*STZ packed pairs
    const int t   = blockIdx.x;                    // 0..511
    const int img = t & 1;
    const int s   = t >> 1;                        // 0..255: b(2) x x(128)
    const int b   = s >> 7;
    const int x   = s & 127;
    const int sb  = (b * 128 + x) * 16384;         // + y*128 + z
    const int tid = threadIdx.x;                   // 0..1023
    const float* im = img ? tgt : pred;
    if (t == 0 && tid == 0) out[0] = 0.0f;         // done before xloss dispatch

    // ---- stage ONCE: batch 16 slab loads (two-phase, proven R14/R17) ----
    float vreg[16];
#pragma unroll
    for (int k = 0; k < 16; ++k) vreg[k] = im[sb + tid + k * 1024];

    // ---- ballots ONCE: fg site bitmasks (bg masks = complement) ----
#pragma unroll
    for (int k = 0; k < 16; ++k) {
        bool fg = vreg[k] > 0.5f;
        unsigned long long bal = __ballot(fg);
        if ((tid & 63) == 0) bm[(tid + k * 1024) >> 6] = bal; // uniform per wave
    }
    __syncthreads();

    unsigned short* hu = (unsigned short*)hz;
    const int z = tid & 127;                       // fixed per thread, uniform/wave
    const int c = tid & 127;
    const int g = tid >> 7;                        // 0..7, wave-uniform
    const int xsq = x * x;

    // ---- both polarities sequentially, reusing bm (read-only) and hz ----
#pragma clang loop unroll(disable)
    for (int pol = 0; pol < 2; ++pol) {            // 0: fg EDT (sites=~fg), 1: bg
        // parallel z-EDT: 16 y-rows per thread
#pragma unroll
        for (int k = 0; k < 16; ++k) {
            int y = g + k * 8;
            unsigned long long b0 = bm[2 * y], b1 = bm[2 * y + 1];
            unsigned long long m0 = pol ? b0 : ~b0;  // block-uniform select
            unsigned long long m1 = pol ? b1 : ~b1;
            int d;
            if (z < 64) {
                unsigned long long lm = m0 << (63 - z);
                unsigned long long rm = m0 >> z;
                int dfwd = lm ? __builtin_clzll(lm) : 999;
                int db0  = rm ? __builtin_ctzll(rm) : 999;
                int db1  = (m1 ? __builtin_ctzll(m1) : 999) + (64 - z);
                d = min(dfwd, min(db0, db1));
            } else {
                int zz = z - 64;
                unsigned long long lm = m1 << (63 - zz);
                unsigned long long rm = m1 >> zz;
                int df1 = lm ? __builtin_clzll(lm) : 999;
                int df0 = (m0 ? __builtin_clzll(m0) : 999) + zz + 1;
                int dbw = rm ? __builtin_ctzll(rm) : 999;
                d = min(min(df1, df0), dbw);
            }
            int f = (d <= 127) ? d * d : BIGI;     // empty line -> BIG (exact)
            hu[((y >> 1) * STZ) * 2 + (y & 1) + 2 * z] = (unsigned short)(f + y * y);
        }
        __syncthreads();

        // y-envelope: ONE round -- 8 wave-groups x 16 rows = 128 outputs
        unsigned short* outv = ws + (size_t)(img * 2 + pol) * NVOX + sb;
        {
            const int i0 = g * 16;                 // wave-uniform
            const float i0f = (float)i0;
            const int W = window_of(hz + c, STZ, i0);
            const int qlo = __builtin_amdgcn_readfirstlane(max(0, (i0 - W) >> 1));
            const int qhi = __builtin_amdgcn_readfirstlane(min(63, (i0 + 15 + W) >> 1));
            float acc[16];
#pragma unroll
            for (int k = 0; k < 16; ++k) acc[k] = 3.0e38f;
            envelope_win(hz + c, STZ, i0f, qlo, qhi, acc);
#pragma unroll
            for (int k = 0; k < 16; ++k) {         // g + x^2 <= 65282: u16
                float iif = i0f + (float)k;
                outv[(i0 + k) * 128 + c] =
                    (unsigned short)((unsigned int)fmaf(iif, iif, acc[k]) + xsq);
            }
        }
        if (pol == 0) __syncthreads();             // hz reused by pol1 z-EDT
    }
}

// Fused dual-polarity x-envelope + loss partial (R18 proven body).
// 64-col tiles, 512 thr, 33.6KB LDS. Grid 1024 = (img, b, 256 tiles).
__global__ __launch_bounds__(512) void xloss_kernel(const float* __restrict__ pred,
                                                    const float* __restrict__ tgt,
                                                    const unsigned short* __restrict__ ws,
                                                    float* __restrict__ out) {
    __shared__ __align__(16) unsigned int hx[129 * STX];   // 128 rows + 1 slack
    __shared__ float red[8];
    const int t    = blockIdx.x;
    const int img  = t & 1;                    // adjacent blocks share pred/tgt
    const int b    = (t >> 1) & 1;
    const int q0   = (t >> 2) * 64;            // (y,z) tile base, 0..16320
    const int base = b * 2097152 + q0;         // + x*16384 + c
    const int tid  = threadIdx.x;
    const int c    = tid & 63;
    const int i0   = (tid >> 6) * 16;          // wave-uniform (64 lanes = 64 cols)
    const float i0f = (float)i0;
    const unsigned short* A16 = ws + (size_t)(img * 2) * NVOX;
    const unsigned int* A32 = (const unsigned int*)(A16 + base);       // base even
    const unsigned int* B32 = (const unsigned int*)(A16 + NVOX + base);

    // hoisted scattered pred/tgt loads: latency hides under the scan
    float dv[16];
#pragma unroll
    for (int k = 0; k < 16; ++k) {
        int v = base + (i0 + k) * 16384 + c;   // 256B contiguous per wave
        dv[k] = pred[v] - tgt[v];
    }

    // stage BOTH volumes, u32 in AND out: word[j][c] = hA | hB<<16
#pragma unroll
    for (int k = 0; k < 8; ++k) {
        int l = tid + k * 512;                 // 0..4095
        int j = l >> 5, cp = l & 31;           // row j, u32 col-pair (c=2cp,2cp+1)
        unsigned int va = A32[j * 8192 + cp];
        unsigned int vb = B32[j * 8192 + cp];
        int w0 = j * STX + 2 * cp;
        hx[w0]     = (va & 0xffffu) | (vb << 16);          // col 2cp
        hx[w0 + 1] = (va >> 16)    | (vb & 0xffff0000u);   // col 2cp+1
    }
    __syncthreads();

    // window over both polarities + no-fg guard from fmxB
    const unsigned int* p = hx + c;
    int fmxA = 0, fmxB = 0;
#pragma unroll
    for (int m = 0; m < 16; ++m) {
        int j = i0 + m;
        unsigned int w = p[j * STX];
        fmxA = max(fmxA, (int)(w & 0xffffu) - j * j);  // f = h - j^2 >= 0
        fmxB = max(fmxB, (int)(w >> 16) - j * j);
    }
    int fmx = max(fmxA, fmxB);
#pragma unroll
    for (int off = 32; off; off >>= 1) {
        fmx  = max(fmx,  __shfl_xor(fmx,  off));
        fmxB = max(fmxB, __shfl_xor(fmxB, off));
    }
    int W = (int)sqrtf((float)fmx);
    W += (W * W < fmx);
    W += (W * W < fmx);                        // W*W >= fmx
    const int jlo = __builtin_amdgcn_readfirstlane(max(0, i0 - W));
    const int jhi = __builtin_amdgcn_readfirstlane(min(127, i0 + 15 + W));
    // bg-EDT f == BIGI uniformly iff sample has no fg (else <= 48387 < BIGI)
    const bool nofg = (fmxB >= BIGI);

    // fused scan: accA (pol0) + accB (pol1) in one pass, 1-ahead
    float accA[16], accB[16];
#pragma unroll
    for (int k = 0; k < 16; ++k) { accA[k] = 3.0e38f; accB[k] = 3.0e38f; }
    unsigned int vc = p[jlo * STX];
    float jm = -2.0f * (float)jlo;
    for (int j = jlo; j <= jhi; ++j) {
        unsigned int vn = p[(j + 1) * STX];    // row 128 slack exists
        float hA = (float)(vc & 0xffffu);
        float hB = (float)(vc >> 16);
        float cA = fmaf(jm, i0f, hA);          // candidate at i = i0
        float cB = fmaf(jm, i0f, hB);
#pragma unroll
        for (int k = 0; k < 16; ++k) {
            accA[k] = fminf(accA[k], cA);
            accB[k] = fminf(accB[k], cB);
            cA += jm; cB += jm;                // exact: integers < 2^17
        }
        jm -= 2.0f;
        vc = vn;
    }

    // loss partial: (p-t)^2 * (sqrt(gA)+sqrt(gB))^2 * guard
    // (sqrt-then-square kept: reference computes (sqrt g)**2, bit-compat)
    float s = 0.0f;
#pragma unroll
    for (int k = 0; k < 16; ++k) {
        float iif = i0f + (float)k;
        float gA = fmaf(iif, iif, accA[k]);
        float gB = fmaf(iif, iif, accB[k]);
        float d = dv[k];
        float fld = sqrtf(gA) + sqrtf(gB);
        s += d * d * fld * fld;
    }
    if (nofg) s = 0.0f;
#pragma unroll
    for (int off = 32; off > 0; off >>= 1) s += __shfl_down(s, off);
    if ((tid & 63) == 0) red[tid >> 6] = s;
    __syncthreads();
    if (tid == 0) {
        float tot = 0.0f;
#pragma unroll
        for (int w = 0; w < 8; ++w) tot += red[w];
        atomicAdd(out, tot * (1.0f / 4194304.0f));
    }
}

extern "C" void kernel_launch(void* const* d_in, const int* in_sizes, int n_in,
                              void* d_out, int out_size, void* d_ws, size_t ws_size,
                              hipStream_t stream) {
    const float* pred = (const float*)d_in[0];
    const float* tgt  = (const float*)d_in[1];
    float* out = (float*)d_out;
    unsigned short* ws16 = (unsigned short*)d_ws;      // 4 u16 volumes = 33.6 MB

    zy_kernel<<<dim3(512), 1024, 0, stream>>>(pred, tgt, ws16, out);
    xloss_kernel<<<dim3(1024), 512, 0, stream>>>(pred, tgt, ws16, out);
}

// Round 13
// 154.425 us; speedup vs baseline: 1.0490x; 1.0332x over previous
//
#include <hip/hip_runtime.h>

// HausdorffDTLoss: exact separable EDT (fg & bg) per image, then
// mean((pred-target)^2 * (pred_dt^2 + target_dt^2)).
// Envelope identity: g[i] = min_j f[j]+(i-j)^2 = i^2 + min_j (h[j]-2ij),
// h[j]=f[j]+j^2. All intermediates are integers, |val| < 2^17 -> u16 storage,
// fp32 math exact (R1-R21: absmax 0.0).
// R12 windowing: scan only |i-j| <= W, W = ceil(sqrt(max f over outputs)) --
// exact for any input (j=i in-window; outside candidates >= f(i) >= g(i)).
//
// R22. Polarity-merge verdict after R20 (512blk/512thr: 57-61us) and R21
// (512blk/1024thr: 53.5us, occ 34%): merge saves only ~7% of instructions
// (stage) but costs occupancy/convoying in every packaging -- zy was never
// fetch-bound (12% HBM). REVERT zy to R18's split-polarity form (proven 46us,
// 1024blk x 512thr, 4 blocks/CU). NEW: FMA-form envelope candidates in zy --
// precompute ik[k]=i0f+k, inner becomes c=fmaf(jm,ik[k],h) + fmin: the two
// 16-deep serial add-chains (4cyc/link dep latency, the ~20% VALU stall)
// become 16 independent (fma->fmin) pairs. Op count unchanged, ILP maximal,
// exact (all integers < 2^17). xloss byte-identical (proven 46us, VGPR 48 --
// no headroom for an ik table without risking the 64-VGPR cliff).

constexpr int BIGI = 49153;      // 3*128^2+1, matches reference BIG exactly
constexpr int NVOX = 4194304;    // voxels per tensor (2 samples x 128^3)
constexpr int STZ  = 129;        // zy dword row stride: 129%32=1 -> 2-way max (free)
constexpr int STX  = 65;         // xloss dword row stride: 65%32=1 -> same property
constexpr int LDSW = 512 + 65 * STZ;   // bm(256 u64 = 512 w) + hz(65*129 w) = 35.6KB

// Windowed pair-packed lower-envelope into acc[16] at outputs i0..i0+15,
// FMA-form: candidates recomputed per (q,k) from ik[k] -- no serial chains.
// p = column c of a [65*stride] u32 LDS array of packed u16 h-values
// (row 64 = slack for the 1-ahead prefetch).
__device__ __forceinline__ void envelope_fma(const unsigned int* __restrict__ p,
                                             const int stride,
                                             const float* __restrict__ ik,
                                             const int qlo, const int qhi,
                                             float acc[16]) {
    unsigned int vc = p[qlo * stride];
    float jm2 = -4.0f * (float)qlo;            // -2*(2q)
    for (int q = qlo; q <= qhi; ++q) {
        unsigned int vn = p[(q + 1) * stride]; // 1-pair prefetch (slack row)
        float h0 = (float)(vc & 0xffffu);      // j = 2q
        float h1 = (float)(vc >> 16);          // j = 2q+1
        float jb = jm2 - 2.0f;
#pragma unroll
        for (int k = 0; k < 16; ++k) {         // 16 independent fma->fmin pairs
            float c0 = fmaf(jm2, ik[k], h0);   // exact: |jm2*i + h| < 2^17
            float c1 = fmaf(jb,  ik[k], h1);
            acc[k] = fminf(acc[k], fminf(c0, c1));
        }
        jm2 -= 4.0f;
        vc = vn;
    }
}

// Wave-uniform window W from the wave's 16 output rows' f-values (pair-packed
// layout; f = h - i^2), wave-maxed. Guarantees W*W >= fmax.
__device__ __forceinline__ int window_of(const unsigned int* __restrict__ p,
                                         const int stride, const int i0) {
    int fmx = 0;
#pragma unroll
    for (int m = 0; m < 8; ++m) {
        unsigned int v = p[((i0 >> 1) + m) * stride];
        int y0 = i0 + 2 * m, y1 = y0 + 1;
        int f0 = (int)(v & 0xffffu) - y0 * y0;
        int f1 = (int)(v >> 16) - y1 * y1;
        fmx = max(fmx, max(f0, f1));
    }
#pragma unroll
    for (int off = 32; off; off >>= 1) fmx = max(fmx, __shfl_xor(fmx, off));
    int W = (int)sqrtf((float)fmx);            // fmx <= 49153, exact in fp32
    W += (W * W < fmx);
    W += (W * W < fmx);                        // guarantees W*W >= fmx
    return W;
}

// Split-polarity zy (R18 proven shape): binarize + bitmask z-EDT + windowed
// y-envelope for one (b,x) slab, one image, one polarity. 512 thr, 35.6KB
// LDS, 4 blocks/CU. Grid 1024 = (pol, img, b*x). Stores g + x^2 (u16).
__global__ __launch_bounds__(512) void zy_kernel(const float* __restrict__ pred,
                                                 const float* __restrict__ tgt,
                                                 unsigned short* __restrict__ ws,
                                                 float* __restrict__ out) {
    __shared__ __align__(16) unsigned int lds[LDSW];
    unsigned long long* bm = (unsigned long long*)lds;   // 256 u64 site masks
    unsigned int* hz = lds + 512;                        // 65*STZ packed pairs
    const int t   = blockIdx.x;
    const int pol = t & 1;                         // 0: fg EDT (sites=~fg), 1: bg
    const int img = (t >> 1) & 1;
    const int s   = t >> 2;                        // 0..255: b(2) x x(128)
    const int b   = s >> 7;
    const int x   = s & 127;
    const int sb  = (b * 128 + x) * 16384;         // + y*128 + z
    const int tid = threadIdx.x;
    const float* im = img ? tgt : pred;
    if (t == 0 && tid == 0) out[0] = 0.0f;         // done before xloss dispatch

    // ---- stage phase 1: batch ALL 32 slab loads (two-phase, proven R14) ----
    float vreg[32];
#pragma unroll
    for (int k = 0; k < 32; ++k) vreg[k] = im[sb + tid + k * 512];

    // ---- stage phase 2: ballots -> site bitmasks ----
#pragma unroll
    for (int k = 0; k < 32; ++k) {
        bool fg = vreg[k] > 0.5f;
        bool site = pol ? fg : !fg;
        unsigned long long bal = __ballot(site);
        if ((tid & 63) == 0) bm[(tid + k * 512) >> 6] = bal; // uniform per wave
    }
    __syncthreads();

    // ---- parallel z-EDT: per-voxel nearest-site distance from the masks ----
    unsigned short* hu = (unsigned short*)hz;
    const int z = tid & 127;                       // fixed per thread, uniform/wave
#pragma unroll
    for (int k = 0; k < 32; ++k) {
        int y = (tid >> 7) + k * 4;
        unsigned long long m0 = bm[2 * y], m1 = bm[2 * y + 1];
        int d;
        if (z < 64) {
            unsigned long long lm = m0 << (63 - z);
            unsigned long long rm = m0 >> z;
            int dfwd = lm ? __builtin_clzll(lm) : 999;
            int db0  = rm ? __builtin_ctzll(rm) : 999;
            int db1  = (m1 ? __builtin_ctzll(m1) : 999) + (64 - z);
            d = min(dfwd, min(db0, db1));
        } else {
            int zz = z - 64;
            unsigned long long lm = m1 << (63 - zz);
            unsigned long long rm = m1 >> zz;
            int df1 = lm ? __builtin_clzll(lm) : 999;
            int df0 = (m0 ? __builtin_clzll(m0) : 999) + zz + 1;
            int dbw = rm ? __builtin_ctzll(rm) : 999;
            d = min(min(df1, df0), dbw);
        }
        int f = (d <= 127) ? d * d : BIGI;         // empty line -> BIG (exact)
        hu[((y >> 1) * STZ) * 2 + (y & 1) + 2 * z] = (unsigned short)(f + y * y);
    }
    __syncthreads();

    // ---- y-envelope: c = z column, 4 groups x 2 rounds; store g + x^2 ----
    unsigned short* outv = ws + (size_t)(img * 2 + pol) * NVOX + sb;
    const int c = tid & 127;
    const int xsq = x * x;
#pragma clang loop unroll(disable)
    for (int r = 0; r < 2; ++r) {                  // one acc[16] live at a time
        const int i0 = (tid >> 7) * 16 + r * 64;   // wave-uniform (tid>>7)
        const float i0f = (float)i0;
        float ik[16];
#pragma unroll
        for (int k = 0; k < 16; ++k) ik[k] = i0f + (float)k;
        const int W = window_of(hz + c, STZ, i0);
        const int qlo = __builtin_amdgcn_readfirstlane(max(0, (i0 - W) >> 1));
        const int qhi = __builtin_amdgcn_readfirstlane(min(63, (i0 + 15 + W) >> 1));
        float acc[16];
#pragma unroll
        for (int k = 0; k < 16; ++k) acc[k] = 3.0e38f;
        envelope_fma(hz + c, STZ, ik, qlo, qhi, acc);
#pragma unroll
        for (int k = 0; k < 16; ++k) {             // g + x^2 <= 65282: u16
            outv[(i0 + k) * 128 + c] =
                (unsigned short)((unsigned int)fmaf(ik[k], ik[k], acc[k]) + xsq);
        }
    }
}

// Fused dual-polarity x-envelope + loss partial (R18 proven body, unchanged).
// 64-col tiles, 512 thr, 33.6KB LDS. Grid 1024 = (img, b, 256 tiles).
__global__ __launch_bounds__(512) void xloss_kernel(const float* __restrict__ pred,
                                                    const float* __restrict__ tgt,
                                                    const unsigned short* __restrict__ ws,
                                                    float* __restrict__ out) {
    __shared__ __align__(16) unsigned int hx[129 * STX];   // 128 rows + 1 slack
    __shared__ float red[8];
    const int t    = blockIdx.x;
    const int img  = t & 1;                    // adjacent blocks share pred/tgt
    const int b    = (t >> 1) & 1;
    const int q0   = (t >> 2) * 64;            // (y,z) tile base, 0..16320
    const int base = b * 2097152 + q0;         // + x*16384 + c
    const int tid  = threadIdx.x;
    const int c    = tid & 63;
    const int i0   = (tid >> 6) * 16;          // wave-uniform (64 lanes = 64 cols)
    const float i0f = (float)i0;
    const unsigned short* A16 = ws + (size_t)(img * 2) * NVOX;
    const unsigned int* A32 = (const unsigned int*)(A16 + base);       // base even
    const unsigned int* B32 = (const unsigned int*)(A16 + NVOX + base);

    // hoisted scattered pred/tgt loads: latency hides under the scan
    float dv[16];
#pragma unroll
    for (int k = 0; k < 16; ++k) {
        int v = base + (i0 + k) * 16384 + c;   // 256B contiguous per wave
        dv[k] = pred[v] - tgt[v];
    }

    // stage BOTH volumes, u32 in AND out: word[j][c] = hA | hB<<16
#pragma unroll
    for (int k = 0; k < 8; ++k) {
        int l = tid + k * 512;                 // 0..4095
        int j = l >> 5, cp = l & 31;           // row j, u32 col-pair (c=2cp,2cp+1)
        unsigned int va = A32[j * 8192 + cp];
        unsigned int vb = B32[j * 8192 + cp];
        int w0 = j * STX + 2 * cp;
        hx[w0]     = (va & 0xffffu) | (vb << 16);          // col 2cp
        hx[w0 + 1] = (va >> 16)    | (vb & 0xffff0000u);   // col 2cp+1
    }
    __syncthreads();

    // window over both polarities + no-fg guard from fmxB
    const unsigned int* p = hx + c;
    int fmxA = 0, fmxB = 0;
#pragma unroll
    for (int m = 0; m < 16; ++m) {
        int j = i0 + m;
        unsigned int w = p[j * STX];
        fmxA = max(fmxA, (int)(w & 0xffffu) - j * j);  // f = h - j^2 >= 0
        fmxB = max(fmxB, (int)(w >> 16) - j * j);
    }
    int fmx = max(fmxA, fmxB);
#pragma unroll
    for (int off = 32; off; off >>= 1) {
        fmx  = max(fmx,  __shfl_xor(fmx,  off));
        fmxB = max(fmxB, __shfl_xor(fmxB, off));
    }
    int W = (int)sqrtf((float)fmx);
    W += (W * W < fmx);
    W += (W * W < fmx);                        // W*W >= fmx
    const int jlo = __builtin_amdgcn_readfirstlane(max(0, i0 - W));
    const int jhi = __builtin_amdgcn_readfirstlane(min(127, i0 + 15 + W));
    // bg-EDT f == BIGI uniformly iff sample has no fg (else <= 48387 < BIGI)
    const bool nofg = (fmxB >= BIGI);

    // fused scan: accA (pol0) + accB (pol1) in one pass, 1-ahead
    float accA[16], accB[16];
#pragma unroll
    for (int k = 0; k < 16; ++k) { accA[k] = 3.0e38f; accB[k] = 3.0e38f; }
    unsigned int vc = p[jlo * STX];
    float jm = -2.0f * (float)jlo;
    for (int j = jlo; j <= jhi; ++j) {
        unsigned int vn = p[(j + 1) * STX];    // row 128 slack exists
        float hA = (float)(vc & 0xffffu);
        float hB = (float)(vc >> 16);
        float cA = fmaf(jm, i0f, hA);          // candidate at i = i0
        float cB = fmaf(jm, i0f, hB);
#pragma unroll
        for (int k = 0; k < 16; ++k) {
            accA[k] = fminf(accA[k], cA);
            accB[k] = fminf(accB[k], cB);
            cA += jm; cB += jm;                // exact: integers < 2^17
        }
        jm -= 2.0f;
        vc = vn;
    }

    // loss partial: (p-t)^2 * (sqrt(gA)+sqrt(gB))^2 * guard
    // (sqrt-then-square kept: reference computes (sqrt g)**2, bit-compat)
    float s = 0.0f;
#pragma unroll
    for (int k = 0; k < 16; ++k) {
        float iif = i0f + (float)k;
        float gA = fmaf(iif, iif, accA[k]);
        float gB = fmaf(iif, iif, accB[k]);
        float d = dv[k];
        float fld = sqrtf(gA) + sqrtf(gB);
        s += d * d * fld * fld;
    }
    if (nofg) s = 0.0f;
#pragma unroll
    for (int off = 32; off > 0; off >>= 1) s += __shfl_down(s, off);
    if ((tid & 63) == 0) red[tid >> 6] = s;
    __syncthreads();
    if (tid == 0) {
        float tot = 0.0f;
#pragma unroll
        for (int w = 0; w < 8; ++w) tot += red[w];
        atomicAdd(out, tot * (1.0f / 4194304.0f));
    }
}

extern "C" void kernel_launch(void* const* d_in, const int* in_sizes, int n_in,
                              void* d_out, int out_size, void* d_ws, size_t ws_size,
                              hipStream_t stream) {
    const float* pred = (const float*)d_in[0];
    const float* tgt  = (const float*)d_in[1];
    float* out = (float*)d_out;
    unsigned short* ws16 = (unsigned short*)d_ws;      // 4 u16 volumes = 33.6 MB

    zy_kernel<<<dim3(1024), 512, 0, stream>>>(pred, tgt, ws16, out);
    xloss_kernel<<<dim3(1024), 512, 0, stream>>>(pred, tgt, ws16, out);
}

// Round 14
// 150.435 us; speedup vs baseline: 1.0768x; 1.0265x over previous
//
#include <hip/hip_runtime.h>

// HausdorffDTLoss: exact separable EDT (fg & bg) per image, then
// mean((pred-target)^2 * (pred_dt^2 + target_dt^2)).
// Envelope identity: g[i] = min_j f[j]+(i-j)^2 = i^2 + min_j (h[j]-2ij),
// h[j]=f[j]+j^2. All intermediates are integers, |val| < 2^17 -> u16 storage,
// fp32 math exact (R1-R22: absmax 0.0).
// R12 windowing: scan only |i-j| <= W, W = ceil(sqrt(max f over outputs)) --
// exact for any input (j=i in-window; outside candidates >= f(i) >= g(i)).
//
// R23 = full revert to the R18-proven bodies (best measured: 149.5us;
// zy 46us VGPR 28, xloss 46us VGPR 48). Lever ledger, all resolved:
//   kept:  R12 windowing; R14 two-phase stage; R17 flags-elimination +
//          dv-hoist + fused dual-polarity xloss scan; 2-dispatch pipeline.
//   dead:  polarity merge (R20 512x512: 57-61us; R21 512x1024: 53.5us --
//          zy is not fetch-bound, packaging costs occupancy every time);
//          grid-barrier fusion (R19: 1024 blocks NOT co-resident, absmax
//          4959); cooperative launch (R16: fails under graph capture);
//          inner-loop restructurings (R11 asm-min3/pk, R15 2-deep ring,
//          R22 FMA-form+ik-table: all regressed -- the VOP2 chain form at
//          VGPR 28 is the issue-rate optimum; residual ~20% VALU idle is
//          barrier/LDS-latency structural).
// Remaining gap to total is ~57us of harness-fixed graph/reset overhead
// (R17->R18: node removal moved total ~1us).

constexpr int BIGI = 49153;      // 3*128^2+1, matches reference BIG exactly
constexpr int NVOX = 4194304;    // voxels per tensor (2 samples x 128^3)
constexpr int STZ  = 129;        // zy dword row stride: 129%32=1 -> 2-way max (free)
constexpr int STX  = 65;         // xloss dword row stride: 65%32=1 -> same property
constexpr int LDSW = 512 + 65 * STZ;   // bm(256 u64 = 512 w) + hz(65*129 w) = 35.6KB

// Windowed pair-packed lower-envelope into acc[16] at outputs i0..i0+15.
// p = column c of a [65*stride] u32 LDS array of packed u16 h-values
// (row 64 = slack for the 1-ahead prefetch). R14 proven chain form.
__device__ __forceinline__ void envelope_win(const unsigned int* __restrict__ p,
                                             const int stride, const float i0f,
                                             const int qlo, const int qhi,
                                             float acc[16]) {
    unsigned int vc = p[qlo * stride];
    float jm2 = -4.0f * (float)qlo;            // -2*(2q)
    for (int q = qlo; q <= qhi; ++q) {
        unsigned int vn = p[(q + 1) * stride]; // 1-pair prefetch (slack row)
        float h0 = (float)(vc & 0xffffu);      // j = 2q
        float h1 = (float)(vc >> 16);          // j = 2q+1
        float jb = jm2 - 2.0f;
        float c0 = fmaf(jm2, i0f, h0);         // candidate at i = i0
        float c1 = fmaf(jb,  i0f, h1);
#pragma unroll
        for (int k = 0; k < 16; ++k) {
            acc[k] = fminf(acc[k], fminf(c0, c1));
            c0 += jm2; c1 += jb;               // exact: integers < 2^17
        }
        jm2 -= 4.0f;
        vc = vn;
    }
}

// Wave-uniform window W from the wave's 16 output rows' f-values (pair-packed
// layout; f = h - i^2), wave-maxed. Guarantees W*W >= fmax.
__device__ __forceinline__ int window_of(const unsigned int* __restrict__ p,
                                         const int stride, const int i0) {
    int fmx = 0;
#pragma unroll
    for (int m = 0; m < 8; ++m) {
        unsigned int v = p[((i0 >> 1) + m) * stride];
        int y0 = i0 + 2 * m, y1 = y0 + 1;
        int f0 = (int)(v & 0xffffu) - y0 * y0;
        int f1 = (int)(v >> 16) - y1 * y1;
        fmx = max(fmx, max(f0, f1));
    }
#pragma unroll
    for (int off = 32; off; off >>= 1) fmx = max(fmx, __shfl_xor(fmx, off));
    int W = (int)sqrtf((float)fmx);            // fmx <= 49153, exact in fp32
    W += (W * W < fmx);
    W += (W * W < fmx);                        // guarantees W*W >= fmx
    return W;
}

// Split-polarity zy (R18 proven): binarize + bitmask z-EDT + windowed
// y-envelope for one (b,x) slab, one image, one polarity. 512 thr, 35.6KB
// LDS, 4 blocks/CU. Grid 1024 = (pol, img, b*x). Stores g + x^2 (u16).
__global__ __launch_bounds__(512) void zy_kernel(const float* __restrict__ pred,
                                                 const float* __restrict__ tgt,
                                                 unsigned short* __restrict__ ws,
                                                 float* __restrict__ out) {
    __shared__ __align__(16) unsigned int lds[LDSW];
    unsigned long long* bm = (unsigned long long*)lds;   // 256 u64 site masks
    unsigned int* hz = lds + 512;                        // 65*STZ packed pairs
    const int t   = blockIdx.x;
    const int pol = t & 1;                         // 0: fg EDT (sites=~fg), 1: bg
    const int img = (t >> 1) & 1;
    const int s   = t >> 2;                        // 0..255: b(2) x x(128)
    const int b   = s >> 7;
    const int x   = s & 127;
    const int sb  = (b * 128 + x) * 16384;         // + y*128 + z
    const int tid = threadIdx.x;
    const float* im = img ? tgt : pred;
    if (t == 0 && tid == 0) out[0] = 0.0f;         // done before xloss dispatch

    // ---- stage phase 1: batch ALL 32 slab loads (two-phase, proven R14) ----
    float vreg[32];
#pragma unroll
    for (int k = 0; k < 32; ++k) vreg[k] = im[sb + tid + k * 512];

    // ---- stage phase 2: ballots -> site bitmasks ----
#pragma unroll
    for (int k = 0; k < 32; ++k) {
        bool fg = vreg[k] > 0.5f;
        bool site = pol ? fg : !fg;
        unsigned long long bal = __ballot(site);
        if ((tid & 63) == 0) bm[(tid + k * 512) >> 6] = bal; // uniform per wave
    }
    __syncthreads();

    // ---- parallel z-EDT: per-voxel nearest-site distance from the masks ----
    unsigned short* hu = (unsigned short*)hz;
    const int z = tid & 127;                       // fixed per thread, uniform/wave
#pragma unroll
    for (int k = 0; k < 32; ++k) {
        int y = (tid >> 7) + k * 4;
        unsigned long long m0 = bm[2 * y], m1 = bm[2 * y + 1];
        int d;
        if (z < 64) {
            unsigned long long lm = m0 << (63 - z);
            unsigned long long rm = m0 >> z;
            int dfwd = lm ? __builtin_clzll(lm) : 999;
            int db0  = rm ? __builtin_ctzll(rm) : 999;
            int db1  = (m1 ? __builtin_ctzll(m1) : 999) + (64 - z);
            d = min(dfwd, min(db0, db1));
        } else {
            int zz = z - 64;
            unsigned long long lm = m1 << (63 - zz);
            unsigned long long rm = m1 >> zz;
            int df1 = lm ? __builtin_clzll(lm) : 999;
            int df0 = (m0 ? __builtin_clzll(m0) : 999) + zz + 1;
            int dbw = rm ? __builtin_ctzll(rm) : 999;
            d = min(min(df1, df0), dbw);
        }
        int f = (d <= 127) ? d * d : BIGI;         // empty line -> BIG (exact)
        hu[((y >> 1) * STZ) * 2 + (y & 1) + 2 * z] = (unsigned short)(f + y * y);
    }
    __syncthreads();

    // ---- y-envelope: c = z column, 4 groups x 2 rounds; store g + x^2 ----
    unsigned short* outv = ws + (size_t)(img * 2 + pol) * NVOX + sb;
    const int c = tid & 127;
    const int xsq = x * x;
#pragma clang loop unroll(disable)
    for (int r = 0; r < 2; ++r) {                  // one acc[16] live at a time
        const int i0 = (tid >> 7) * 16 + r * 64;   // wave-uniform (tid>>7)
        const float i0f = (float)i0;
        const int W = window_of(hz + c, STZ, i0);
        const int qlo = __builtin_amdgcn_readfirstlane(max(0, (i0 - W) >> 1));
        const int qhi = __builtin_amdgcn_readfirstlane(min(63, (i0 + 15 + W) >> 1));
        float acc[16];
#pragma unroll
        for (int k = 0; k < 16; ++k) acc[k] = 3.0e38f;
        envelope_win(hz + c, STZ, i0f, qlo, qhi, acc);
#pragma unroll
        for (int k = 0; k < 16; ++k) {             // g + x^2 <= 65282: u16
            float iif = i0f + (float)k;
            outv[(i0 + k) * 128 + c] =
                (unsigned short)((unsigned int)fmaf(iif, iif, acc[k]) + xsq);
        }
    }
}

// Fused dual-polarity x-envelope + loss partial (R18 proven body, unchanged).
// 64-col tiles, 512 thr, 33.6KB LDS. Grid 1024 = (img, b, 256 tiles).
__global__ __launch_bounds__(512) void xloss_kernel(const float* __restrict__ pred,
                                                    const float* __restrict__ tgt,
                                                    const unsigned short* __restrict__ ws,
                                                    float* __restrict__ out) {
    __shared__ __align__(16) unsigned int hx[129 * STX];   // 128 rows + 1 slack
    __shared__ float red[8];
    const int t    = blockIdx.x;
    const int img  = t & 1;                    // adjacent blocks share pred/tgt
    const int b    = (t >> 1) & 1;
    const int q0   = (t >> 2) * 64;            // (y,z) tile base, 0..16320
    const int base = b * 2097152 + q0;         // + x*16384 + c
    const int tid  = threadIdx.x;
    const int c    = tid & 63;
    const int i0   = (tid >> 6) * 16;          // wave-uniform (64 lanes = 64 cols)
    const float i0f = (float)i0;
    const unsigned short* A16 = ws + (size_t)(img * 2) * NVOX;
    const unsigned int* A32 = (const unsigned int*)(A16 + base);       // base even
    const unsigned int* B32 = (const unsigned int*)(A16 + NVOX + base);

    // hoisted scattered pred/tgt loads: latency hides under the scan
    float dv[16];
#pragma unroll
    for (int k = 0; k < 16; ++k) {
        int v = base + (i0 + k) * 16384 + c;   // 256B contiguous per wave
        dv[k] = pred[v] - tgt[v];
    }

    // stage BOTH volumes, u32 in AND out: word[j][c] = hA | hB<<16
#pragma unroll
    for (int k = 0; k < 8; ++k) {
        int l = tid + k * 512;                 // 0..4095
        int j = l >> 5, cp = l & 31;           // row j, u32 col-pair (c=2cp,2cp+1)
        unsigned int va = A32[j * 8192 + cp];
        unsigned int vb = B32[j * 8192 + cp];
        int w0 = j * STX + 2 * cp;
        hx[w0]     = (va & 0xffffu) | (vb << 16);          // col 2cp
        hx[w0 + 1] = (va >> 16)    | (vb & 0xffff0000u);   // col 2cp+1
    }
    __syncthreads();

    // window over both polarities + no-fg guard from fmxB
    const unsigned int* p = hx + c;
    int fmxA = 0, fmxB = 0;
#pragma unroll
    for (int m = 0; m < 16; ++m) {
        int j = i0 + m;
        unsigned int w = p[j * STX];
        fmxA = max(fmxA, (int)(w & 0xffffu) - j * j);  // f = h - j^2 >= 0
        fmxB = max(fmxB, (int)(w >> 16) - j * j);
    }
    int fmx = max(fmxA, fmxB);
#pragma unroll
    for (int off = 32; off; off >>= 1) {
        fmx  = max(fmx,  __shfl_xor(fmx,  off));
        fmxB = max(fmxB, __shfl_xor(fmxB, off));
    }
    int W = (int)sqrtf((float)fmx);
    W += (W * W < fmx);
    W += (W * W < fmx);                        // W*W >= fmx
    const int jlo = __builtin_amdgcn_readfirstlane(max(0, i0 - W));
    const int jhi = __builtin_amdgcn_readfirstlane(min(127, i0 + 15 + W));
    // bg-EDT f == BIGI uniformly iff sample has no fg (else <= 48387 < BIGI)
    const bool nofg = (fmxB >= BIGI);

    // fused scan: accA (pol0) + accB (pol1) in one pass, 1-ahead
    float accA[16], accB[16];
#pragma unroll
    for (int k = 0; k < 16; ++k) { accA[k] = 3.0e38f; accB[k] = 3.0e38f; }
    unsigned int vc = p[jlo * STX];
    float jm = -2.0f * (float)jlo;
    for (int j = jlo; j <= jhi; ++j) {
        unsigned int vn = p[(j + 1) * STX];    // row 128 slack exists
        float hA = (float)(vc & 0xffffu);
        float hB = (float)(vc >> 16);
        float cA = fmaf(jm, i0f, hA);          // candidate at i = i0
        float cB = fmaf(jm, i0f, hB);
#pragma unroll
        for (int k = 0; k < 16; ++k) {
            accA[k] = fminf(accA[k], cA);
            accB[k] = fminf(accB[k], cB);
            cA += jm; cB += jm;                // exact: integers < 2^17
        }
        jm -= 2.0f;
        vc = vn;
    }

    // loss partial: (p-t)^2 * (sqrt(gA)+sqrt(gB))^2 * guard
    // (sqrt-then-square kept: reference computes (sqrt g)**2, bit-compat)
    float s = 0.0f;
#pragma unroll
    for (int k = 0; k < 16; ++k) {
        float iif = i0f + (float)k;
        float gA = fmaf(iif, iif, accA[k]);
        float gB = fmaf(iif, iif, accB[k]);
        float d = dv[k];
        float fld = sqrtf(gA) + sqrtf(gB);
        s += d * d * fld * fld;
    }
    if (nofg) s = 0.0f;
#pragma unroll
    for (int off = 32; off > 0; off >>= 1) s += __shfl_down(s, off);
    if ((tid & 63) == 0) red[tid >> 6] = s;
    __syncthreads();
    if (tid == 0) {
        float tot = 0.0f;
#pragma unroll
        for (int w = 0; w < 8; ++w) tot += red[w];
        atomicAdd(out, tot * (1.0f / 4194304.0f));
    }
}

extern "C" void kernel_launch(void* const* d_in, const int* in_sizes, int n_in,
                              void* d_out, int out_size, void* d_ws, size_t ws_size,
                              hipStream_t stream) {
    const float* pred = (const float*)d_in[0];
    const float* tgt  = (const float*)d_in[1];
    float* out = (float*)d_out;
    unsigned short* ws16 = (unsigned short*)d_ws;      // 4 u16 volumes = 33.6 MB

    zy_kernel<<<dim3(1024), 512, 0, stream>>>(pred, tgt, ws16, out);
    xloss_kernel<<<dim3(1024), 512, 0, stream>>>(pred, tgt, ws16, out);
}